// Round 8
// baseline (142.643 us; speedup 1.0000x reference)
//
#include <hip/hip_runtime.h>
#include <hip/hip_bf16.h>
#include <math.h>

// AKOrN layer: B=2, N=1024, D=256, H=4 (dk=64), O=8, DT=0.1, STEPS=5
// Plain launches only (cooperative kernel killed the container in R6).
//   k_projm : inline dtype-detect + bf16 cvt; MFMA GEMM ->
//             Qb(x0.125) bf16, Kb bf16, PH0 fp32 [bh][o][n], SC0 bf16 sin/cos
//   k_scores: 512 blk, direct-global K A-operand, no staging LDS;
//             U = exp(score) bf16, R = 1/rowsum
//   k_step x5: MFMA D[i][16] = U . SC with BOTH operands direct from global
//             (U L3-hot, SC L2-hot); 4-wave j-split + 4 KB LDS reduce;
//             epilogue writes PH + SC ping-pong
//   k_out   : SC-cos @ Wo.T + bo
//
// Workspace:
//   Qb @0 (1M) | Kb @1M (1M) | R @2M (64K resv) | PH0 @2M+64K (256K)
//   PH1 (+256K) | SC0 (+256K) | SC1 (+256K) | U @2M+1088K (16M)

#define NB 1024
#define NH 4
#define DD 256
#define NO 8
#define PI_F      3.14159265358979323846f
#define TWO_PI_F  6.28318530717958647692f
#define INV_2PI_F 0.15915494309189533577f

typedef __attribute__((ext_vector_type(8))) short bf16x8;
typedef __attribute__((ext_vector_type(4))) float f32x4;

__device__ __forceinline__ float b2f_u(unsigned short s) {
    union { unsigned u; float f; } x; x.u = ((unsigned)s) << 16; return x.f;
}
__device__ __forceinline__ unsigned short f2b(float f) {
    union { float f; unsigned u; } v; v.f = f;
    unsigned r = v.u + 0x7FFFu + ((v.u >> 16) & 1u);   // RTNE
    return (unsigned short)(r >> 16);
}
template<bool F32>
__device__ __forceinline__ uint4 load_pack8(const void* p, size_t off) {
    if (!F32) return *(const uint4*)((const unsigned short*)p + off);
    const float* fp = (const float*)p + off;
    float4 a = *(const float4*)fp;
    float4 b = *(const float4*)(fp + 4);
    uint4 r;
    r.x = (unsigned)f2b(a.x) | ((unsigned)f2b(a.y) << 16);
    r.y = (unsigned)f2b(a.z) | ((unsigned)f2b(a.w) << 16);
    r.z = (unsigned)f2b(b.x) | ((unsigned)f2b(b.y) << 16);
    r.w = (unsigned)f2b(b.z) | ((unsigned)f2b(b.w) << 16);
    return r;
}
__device__ __forceinline__ void load8_rt(int f32, const void* p, int i, float* f) {
    if (f32) {
        const float* fp = (const float*)p + i;
        float4 a = *(const float4*)fp;
        float4 b = *(const float4*)(fp + 4);
        f[0]=a.x; f[1]=a.y; f[2]=a.z; f[3]=a.w;
        f[4]=b.x; f[5]=b.y; f[6]=b.z; f[7]=b.w;
    } else {
        uint4 u = *(const uint4*)((const unsigned short*)p + i);
        f[0] = b2f_u(u.x & 0xFFFFu); f[1] = b2f_u(u.x >> 16);
        f[2] = b2f_u(u.y & 0xFFFFu); f[3] = b2f_u(u.y >> 16);
        f[4] = b2f_u(u.z & 0xFFFFu); f[5] = b2f_u(u.z >> 16);
        f[6] = b2f_u(u.w & 0xFFFFu); f[7] = b2f_u(u.w >> 16);
    }
}
__device__ __forceinline__ float read_cs_bf16(const void* p) {
    float vb = b2f_u(*(const unsigned short*)p);
    bool ok = isfinite(vb) && fabsf(vb) > 1e-30f && fabsf(vb) < 1e30f;
    if (ok) return vb;
    return *(const float*)p;
}
__device__ __forceinline__ int detect_inline(const unsigned short* x) {
    int l = threadIdx.x & 63;
    float a0 = fabsf(b2f_u(x[2 * l]));
    float a1 = fabsf(b2f_u(x[2 * (l + 64)]));
    unsigned long long b0 = __ballot(!(a0 >= 1e-10f && a0 <= 100.0f));
    unsigned long long b1 = __ballot(!(a1 >= 1e-10f && a1 <= 100.0f));
    return (__popcll(b0) + __popcll(b1)) > 16;
}

// ---------------------------------------------------------------------------
// K1: MFMA projection GEMM with inline conversion.
// Grid 288 = 32 i-tiles(64) x 9 f-tiles(64). ftile 0-3 -> Qb(x0.125),
// 4-7 -> Kb, 8 -> PH0(+bp) + SC0.
// ---------------------------------------------------------------------------
template<bool F32>
__device__ void projm_impl(
    const void* __restrict__ x, const void* __restrict__ Wq,
    const void* __restrict__ Wk, const void* __restrict__ Wp,
    const void* __restrict__ bp,
    unsigned short* __restrict__ Qb, unsigned short* __restrict__ Kb,
    float* __restrict__ PH, unsigned short* __restrict__ SC)
{
    __shared__ uint4 Xsh[64 * 32];   // 32 KB
    __shared__ uint4 Wsh[64 * 32];   // 32 KB
    const int tid = threadIdx.x;
    const int ftile = blockIdx.x % 9, itile = blockIdx.x / 9;
    const int i0 = itile * 64, f0 = ftile * 64;
    const int wave = tid >> 6, lane = tid & 63;
    const int n = lane & 15, quad = lane >> 4;

    #pragma unroll
    for (int g = 0; g < 8; g++) {
        int fidx = g * 256 + tid;
        int row = fidx >> 5, q = fidx & 31;
        int sw = (q & 24) | ((q ^ row) & 7);
        Xsh[row * 32 + sw] = load_pack8<F32>(x, (size_t)(i0 + row) * 256 + q * 8);
        int wr = f0 + row;
        uint4 wv = make_uint4(0, 0, 0, 0);
        if (wr < 256)      wv = load_pack8<F32>(Wq, (size_t)wr * 256 + q * 8);
        else if (wr < 512) wv = load_pack8<F32>(Wk, (size_t)(wr - 256) * 256 + q * 8);
        else if (wr < 544) wv = load_pack8<F32>(Wp, (size_t)(wr - 512) * 256 + q * 8);
        Wsh[row * 32 + sw] = wv;
    }
    __syncthreads();

    f32x4 acc[4];
    #pragma unroll
    for (int s = 0; s < 4; s++) acc[s] = (f32x4){0.f, 0.f, 0.f, 0.f};
    const int xrow = wave * 16 + n;
    #pragma unroll
    for (int s = 0; s < 8; s++) {
        int qc = s * 4 + quad;
        bf16x8 b = ((const bf16x8*)Xsh)[xrow * 32 + ((qc & 24) | ((qc ^ xrow) & 7))];
        #pragma unroll
        for (int sub = 0; sub < 4; sub++) {
            int wr = sub * 16 + n;
            bf16x8 a = ((const bf16x8*)Wsh)[wr * 32 + ((qc & 24) | ((qc ^ wr) & 7))];
            acc[sub] = __builtin_amdgcn_mfma_f32_16x16x32_bf16(a, b, acc[sub], 0, 0, 0);
        }
    }

    const int ig = i0 + wave * 16 + n;
    const int bb = ig >> 10, nr = ig & 1023;
    if (ftile < 4) {
        #pragma unroll
        for (int sub = 0; sub < 4; sub++) {
            int dd = sub * 16 + quad * 4;
            ushort4 v = make_ushort4(f2b(acc[sub][0] * 0.125f), f2b(acc[sub][1] * 0.125f),
                                     f2b(acc[sub][2] * 0.125f), f2b(acc[sub][3] * 0.125f));
            *(ushort4*)(Qb + ((size_t)((bb * NH + ftile) * NB + nr)) * 64 + dd) = v;
        }
    } else if (ftile < 8) {
        int h = ftile - 4;
        #pragma unroll
        for (int sub = 0; sub < 4; sub++) {
            int dd = sub * 16 + quad * 4;
            ushort4 v = make_ushort4(f2b(acc[sub][0]), f2b(acc[sub][1]),
                                     f2b(acc[sub][2]), f2b(acc[sub][3]));
            *(ushort4*)(Kb + ((size_t)((bb * NH + h) * NB + nr)) * 64 + dd) = v;
        }
    } else {
        #pragma unroll
        for (int sub = 0; sub < 2; sub++) {
            #pragma unroll
            for (int r = 0; r < 4; r++) {
                int fp = sub * 16 + quad * 4 + r;       // 0..31
                int h2 = fp >> 3, o = fp & 7;
                float bpv = F32 ? ((const float*)bp)[fp]
                                : b2f_u(((const unsigned short*)bp)[fp]);
                float v = acc[sub][r] + bpv;
                int bh = bb * NH + h2;
                PH[(size_t)bh * 8192 + o * 1024 + nr] = v;
                float sv, cv;
                __sincosf(v, &sv, &cv);
                SC[(size_t)(bh * 16 + o) * 1024 + nr]     = f2b(sv);
                SC[(size_t)(bh * 16 + 8 + o) * 1024 + nr] = f2b(cv);
            }
        }
    }
}

__global__ __launch_bounds__(256) void k_projm(
    const unsigned short* x, const void* Wq, const void* Wk, const void* Wp,
    const void* bp, unsigned short* Qb, unsigned short* Kb, float* PH,
    unsigned short* SC)
{
    if (detect_inline(x)) projm_impl<true >(x, Wq, Wk, Wp, bp, Qb, Kb, PH, SC);
    else                  projm_impl<false>(x, Wq, Wk, Wp, bp, Qb, Kb, PH, SC);
}

// ---------------------------------------------------------------------------
// K2: single-pass scores+exp, NO staging LDS. Grid 512 = 8 bh x 64 chunks of
// 16 rows; 4 waves split j into quarters (16 j-tiles each). A-operand (K rows)
// loaded directly from global (Kb is L2-hot: 128 KB/bh shared by 64 blocks).
// ---------------------------------------------------------------------------
__global__ __launch_bounds__(256) void k_scores(
    const unsigned short* __restrict__ Qb, const unsigned short* __restrict__ Kb,
    unsigned short* __restrict__ U, float* __restrict__ R)
{
    __shared__ float redS[4][16];
    const int tid = threadIdx.x;
    const int bh  = blockIdx.x >> 6;
    const int i0  = (blockIdx.x & 63) * 16;
    const int wave = tid >> 6, lane = tid & 63;
    const int n = lane & 15, quad = lane >> 4;

    const unsigned short* qrow = Qb + ((size_t)(bh * NB) + i0 + n) * 64;
    bf16x8 bq0 = *(const bf16x8*)(qrow + quad * 8);
    bf16x8 bq1 = *(const bf16x8*)(qrow + 32 + quad * 8);

    float s = 0.f;
    unsigned short* urow = U + ((size_t)(bh * NB) + i0 + n) * NB;
    const unsigned short* kbase = Kb + ((size_t)(bh * NB) + n) * 64;
    #pragma unroll 2
    for (int t = 0; t < 16; t++) {
        int jt = wave * 16 + t;                       // j-tile 0..63
        const unsigned short* arow = kbase + (size_t)jt * 16 * 64;
        bf16x8 a0 = *(const bf16x8*)(arow + quad * 8);
        bf16x8 a1 = *(const bf16x8*)(arow + 32 + quad * 8);
        f32x4 acc = {0.f, 0.f, 0.f, 0.f};
        acc = __builtin_amdgcn_mfma_f32_16x16x32_bf16(a0, bq0, acc, 0, 0, 0);
        acc = __builtin_amdgcn_mfma_f32_16x16x32_bf16(a1, bq1, acc, 0, 0, 0);
        float u0 = __expf(acc[0]);
        float u1 = __expf(acc[1]);
        float u2 = __expf(acc[2]);
        float u3 = __expf(acc[3]);
        s += (u0 + u1) + (u2 + u3);
        *(ushort4*)(urow + jt * 16 + quad * 4)
            = make_ushort4(f2b(u0), f2b(u1), f2b(u2), f2b(u3));
    }
    s += __shfl_xor(s, 16);
    s += __shfl_xor(s, 32);
    if (lane < 16) redS[wave][lane] = s;
    __syncthreads();
    if (wave == 0 && lane < 16)
        R[bh * NB + i0 + lane]
            = 1.0f / (redS[0][lane] + redS[1][lane] + redS[2][lane] + redS[3][lane]);
}

// ---------------------------------------------------------------------------
// K3: Kuramoto step. Grid 512 = 8 bh x 64 chunks of 16 rows; 4 waves split j
// into quarters (8 MFMAs each). BOTH operands direct from global (U L3-hot,
// SC L2-hot). LDS = 4 KB reduce only; wave-0 epilogue writes PHout + SCout.
// ---------------------------------------------------------------------------
__global__ __launch_bounds__(256) void k_step(
    const unsigned short* __restrict__ xraw,
    const unsigned short* __restrict__ U, const float* __restrict__ R,
    const float* __restrict__ PHin, float* __restrict__ PHout,
    const unsigned short* __restrict__ SCin, unsigned short* __restrict__ SCout,
    const void* __restrict__ omega, const void* __restrict__ csp)
{
    __shared__ f32x4 red[4][64];      // 4 KB
    const int tid  = threadIdx.x;
    const int bh   = blockIdx.x >> 6;
    const int i0   = (blockIdx.x & 63) * 16;
    const int wave = tid >> 6, lane = tid & 63;
    const int n    = lane & 15, quad = lane >> 4;
    const int f32  = detect_inline(xraw);
    const float* phs = PHin + (size_t)bh * 8192;

    const unsigned short* urow  = U + ((size_t)(bh * NB) + i0 + n) * NB;
    const unsigned short* scrow = SCin + (size_t)(bh * 16 + n) * 1024;
    f32x4 acc = {0.f, 0.f, 0.f, 0.f};
    #pragma unroll
    for (int t = 0; t < 8; t++) {
        int it = wave * 8 + t;
        bf16x8 a = *(const bf16x8*)(urow  + it * 32 + quad * 8);
        bf16x8 b = *(const bf16x8*)(scrow + it * 32 + quad * 8);
        acc = __builtin_amdgcn_mfma_f32_16x16x32_bf16(a, b, acc, 0, 0, 0);
    }
    red[wave][lane] = acc;
    __syncthreads();

    if (wave == 0) {
        f32x4 a0 = red[0][lane], a1 = red[1][lane];
        f32x4 a2 = red[2][lane], a3 = red[3][lane];
        #pragma unroll
        for (int v = 0; v < 4; v++) acc[v] = (a0[v] + a1[v]) + (a2[v] + a3[v]);

        float C0 = __shfl_xor(acc[0], 8);
        float C1 = __shfl_xor(acc[1], 8);
        float C2 = __shfl_xor(acc[2], 8);
        float C3 = __shfl_xor(acc[3], 8);

        if (n < 8) {
            const int o = n, h = bh & 3;
            const float cs = f32 ? *(const float*)csp : read_cs_bf16(csp);
            const float om = f32 ? ((const float*)omega)[h * NO + o]
                                 : b2f_u(((const unsigned short*)omega)[h * NO + o]);
            float4 Rv = *(const float4*)(R + bh * NB + i0 + quad * 4);
            float4 pv = *(const float4*)(phs + o * 1024 + i0 + quad * 4);
            float S[4] = {acc[0], acc[1], acc[2], acc[3]};
            float C[4] = {C0, C1, C2, C3};
            float Rr[4] = {Rv.x, Rv.y, Rv.z, Rv.w};
            float P[4]  = {pv.x, pv.y, pv.z, pv.w};
            float op[4];
            #pragma unroll
            for (int r = 0; r < 4; r++) {
                float si, ci;
                __sincosf(P[r], &si, &ci);
                float coup = (ci * S[r] - si * C[r]) * Rr[r];
                float v = P[r] + 0.1f * (om + cs * coup);
                float t2 = v + PI_F;
                t2 -= floorf(t2 * INV_2PI_F) * TWO_PI_F;   // jnp.remainder
                op[r] = t2 - PI_F;
            }
            *(float4*)(PHout + (size_t)bh * 8192 + o * 1024 + i0 + quad * 4)
                = make_float4(op[0], op[1], op[2], op[3]);
            #pragma unroll
            for (int r = 0; r < 4; r++) {
                float sn, cn;
                __sincosf(op[r], &sn, &cn);
                int i = i0 + quad * 4 + r;
                SCout[(size_t)(bh * 16 + o) * 1024 + i]     = f2b(sn);
                SCout[(size_t)(bh * 16 + 8 + o) * 1024 + i] = f2b(cn);
            }
        }
    }
}

// ---------------------------------------------------------------------------
// K4: out = SC_cos @ Wo.T + bo.  Grid 2048 x 256.
// ---------------------------------------------------------------------------
__global__ __launch_bounds__(256) void k_out(
    const unsigned short* __restrict__ xraw,
    const unsigned short* __restrict__ SC,
    const void* __restrict__ Wo, const void* __restrict__ bo,
    void* __restrict__ out)
{
    __shared__ float sig[32];
    const int tid = threadIdx.x;
    const int b = blockIdx.x >> 10, n = blockIdx.x & 1023;
    const int f32 = detect_inline(xraw);
    if (tid < 32) {
        int h = tid >> 3, o = tid & 7;
        sig[tid] = b2f_u(SC[(size_t)((b * NH + h) * 16 + 8 + o) * 1024 + n]);
    }
    __syncthreads();
    float acc = f32 ? ((const float*)bo)[tid] : b2f_u(((const unsigned short*)bo)[tid]);
    #pragma unroll
    for (int d0 = 0; d0 < 32; d0 += 8) {
        float w[8];
        load8_rt(f32, Wo, tid * 32 + d0, w);
        #pragma unroll
        for (int t = 0; t < 8; t++) acc += sig[d0 + t] * w[t];
    }
    size_t oi = (size_t)blockIdx.x * DD + tid;
    if (f32) ((float*)out)[oi] = acc;
    else     ((unsigned short*)out)[oi] = f2b(acc);
}

// ---------------------------------------------------------------------------
extern "C" void kernel_launch(void* const* d_in, const int* in_sizes, int n_in,
                              void* d_out, int out_size, void* d_ws, size_t ws_size,
                              hipStream_t stream)
{
    const unsigned short* x = (const unsigned short*)d_in[0];
    const void* Wq  = d_in[1];
    const void* Wk  = d_in[2];
    const void* Wp  = d_in[3];
    const void* bp  = d_in[4];
    const void* Wo  = d_in[5];
    const void* bo  = d_in[6];
    const void* om  = d_in[7];
    const void* cs  = d_in[8];

    char* w = (char*)d_ws;
    unsigned short* Qb  = (unsigned short*)w;
    unsigned short* Kb  = (unsigned short*)(w + (1u << 20));
    float*          R   = (float*)(w + (2u << 20));
    float*          PH0 = (float*)(w + (2u << 20) + (64u << 10));
    float*          PH1 = (float*)(w + (2u << 20) + (320u << 10));
    unsigned short* SC0 = (unsigned short*)(w + (2u << 20) + (576u << 10));
    unsigned short* SC1 = (unsigned short*)(w + (2u << 20) + (832u << 10));
    unsigned short* U   = (unsigned short*)(w + (2u << 20) + (1088u << 10));

    k_projm <<<288, 256, 0, stream>>>(x, Wq, Wk, Wp, bp, Qb, Kb, PH0, SC0);
    k_scores<<<512, 256, 0, stream>>>(Qb, Kb, U, R);
    k_step<<<512, 256, 0, stream>>>(x, U, R, PH0, PH1, SC0, SC1, om, cs);
    k_step<<<512, 256, 0, stream>>>(x, U, R, PH1, PH0, SC1, SC0, om, cs);
    k_step<<<512, 256, 0, stream>>>(x, U, R, PH0, PH1, SC0, SC1, om, cs);
    k_step<<<512, 256, 0, stream>>>(x, U, R, PH1, PH0, SC1, SC0, om, cs);
    k_step<<<512, 256, 0, stream>>>(x, U, R, PH0, PH1, SC0, SC1, om, cs);
    k_out<<<2048, 256, 0, stream>>>(x, SC1, Wo, bo, d_out);
}

// Round 9
// 134.719 us; speedup vs baseline: 1.0588x; 1.0588x over previous
//
#include <hip/hip_runtime.h>
#include <hip/hip_bf16.h>
#include <math.h>

// AKOrN layer: B=2, N=1024, D=256, H=4 (dk=64), O=8, DT=0.1, STEPS=5
// 7 plain launches:
//   k_projm        : dtype-detect + bf16 cvt; MFMA GEMM -> Qb(x0.125), Kb,
//                    PH0 fp32 [bh][o][n], SC0 bf16 sin/cos
//   k_scores_step1 : scores+exp -> U (global AND 32KB LDS tile), rowsum -> R;
//                    then step-1 MFMA with A from LDS (no global U re-read)
//   k_step x4      : MFMA D[i][16] = U . SC, operands direct from global
//   k_out          : SC-cos @ Wo.T + bo (Wo cached in regs, 8 rows/block)
//
// Workspace:
//   Qb @0 (1M) | Kb @1M (1M) | R @2M (64K resv) | PH0 @2M+64K (256K)
//   PH1 (+256K) | SC0 (+256K) | SC1 (+256K) | U @2M+1088K (16M)

#define NB 1024
#define NH 4
#define DD 256
#define NO 8
#define PI_F      3.14159265358979323846f
#define TWO_PI_F  6.28318530717958647692f
#define INV_2PI_F 0.15915494309189533577f

typedef __attribute__((ext_vector_type(8))) short bf16x8;
typedef __attribute__((ext_vector_type(4))) float f32x4;

__device__ __forceinline__ float b2f_u(unsigned short s) {
    union { unsigned u; float f; } x; x.u = ((unsigned)s) << 16; return x.f;
}
__device__ __forceinline__ unsigned short f2b(float f) {
    union { float f; unsigned u; } v; v.f = f;
    unsigned r = v.u + 0x7FFFu + ((v.u >> 16) & 1u);   // RTNE
    return (unsigned short)(r >> 16);
}
template<bool F32>
__device__ __forceinline__ uint4 load_pack8(const void* p, size_t off) {
    if (!F32) return *(const uint4*)((const unsigned short*)p + off);
    const float* fp = (const float*)p + off;
    float4 a = *(const float4*)fp;
    float4 b = *(const float4*)(fp + 4);
    uint4 r;
    r.x = (unsigned)f2b(a.x) | ((unsigned)f2b(a.y) << 16);
    r.y = (unsigned)f2b(a.z) | ((unsigned)f2b(a.w) << 16);
    r.z = (unsigned)f2b(b.x) | ((unsigned)f2b(b.y) << 16);
    r.w = (unsigned)f2b(b.z) | ((unsigned)f2b(b.w) << 16);
    return r;
}
__device__ __forceinline__ void load8_rt(int f32, const void* p, int i, float* f) {
    if (f32) {
        const float* fp = (const float*)p + i;
        float4 a = *(const float4*)fp;
        float4 b = *(const float4*)(fp + 4);
        f[0]=a.x; f[1]=a.y; f[2]=a.z; f[3]=a.w;
        f[4]=b.x; f[5]=b.y; f[6]=b.z; f[7]=b.w;
    } else {
        uint4 u = *(const uint4*)((const unsigned short*)p + i);
        f[0] = b2f_u(u.x & 0xFFFFu); f[1] = b2f_u(u.x >> 16);
        f[2] = b2f_u(u.y & 0xFFFFu); f[3] = b2f_u(u.y >> 16);
        f[4] = b2f_u(u.z & 0xFFFFu); f[5] = b2f_u(u.z >> 16);
        f[6] = b2f_u(u.w & 0xFFFFu); f[7] = b2f_u(u.w >> 16);
    }
}
__device__ __forceinline__ float read_cs_bf16(const void* p) {
    float vb = b2f_u(*(const unsigned short*)p);
    bool ok = isfinite(vb) && fabsf(vb) > 1e-30f && fabsf(vb) < 1e30f;
    if (ok) return vb;
    return *(const float*)p;
}
__device__ __forceinline__ int detect_inline(const unsigned short* x) {
    int l = threadIdx.x & 63;
    float a0 = fabsf(b2f_u(x[2 * l]));
    float a1 = fabsf(b2f_u(x[2 * (l + 64)]));
    unsigned long long b0 = __ballot(!(a0 >= 1e-10f && a0 <= 100.0f));
    unsigned long long b1 = __ballot(!(a1 >= 1e-10f && a1 <= 100.0f));
    return (__popcll(b0) + __popcll(b1)) > 16;
}

// ---------------------------------------------------------------------------
// K1: MFMA projection GEMM with inline conversion. Grid 288 = 32 i x 9 f.
// ftile 0-3 -> Qb(x0.125), 4-7 -> Kb, 8 -> PH0(+bp) + SC0.
// ---------------------------------------------------------------------------
template<bool F32>
__device__ void projm_impl(
    const void* __restrict__ x, const void* __restrict__ Wq,
    const void* __restrict__ Wk, const void* __restrict__ Wp,
    const void* __restrict__ bp,
    unsigned short* __restrict__ Qb, unsigned short* __restrict__ Kb,
    float* __restrict__ PH, unsigned short* __restrict__ SC)
{
    __shared__ uint4 Xsh[64 * 32];   // 32 KB
    __shared__ uint4 Wsh[64 * 32];   // 32 KB
    const int tid = threadIdx.x;
    const int ftile = blockIdx.x % 9, itile = blockIdx.x / 9;
    const int i0 = itile * 64, f0 = ftile * 64;
    const int wave = tid >> 6, lane = tid & 63;
    const int n = lane & 15, quad = lane >> 4;

    #pragma unroll
    for (int g = 0; g < 8; g++) {
        int fidx = g * 256 + tid;
        int row = fidx >> 5, q = fidx & 31;
        int sw = (q & 24) | ((q ^ row) & 7);
        Xsh[row * 32 + sw] = load_pack8<F32>(x, (size_t)(i0 + row) * 256 + q * 8);
        int wr = f0 + row;
        uint4 wv = make_uint4(0, 0, 0, 0);
        if (wr < 256)      wv = load_pack8<F32>(Wq, (size_t)wr * 256 + q * 8);
        else if (wr < 512) wv = load_pack8<F32>(Wk, (size_t)(wr - 256) * 256 + q * 8);
        else if (wr < 544) wv = load_pack8<F32>(Wp, (size_t)(wr - 512) * 256 + q * 8);
        Wsh[row * 32 + sw] = wv;
    }
    __syncthreads();

    f32x4 acc[4];
    #pragma unroll
    for (int s = 0; s < 4; s++) acc[s] = (f32x4){0.f, 0.f, 0.f, 0.f};
    const int xrow = wave * 16 + n;
    #pragma unroll
    for (int s = 0; s < 8; s++) {
        int qc = s * 4 + quad;
        bf16x8 b = ((const bf16x8*)Xsh)[xrow * 32 + ((qc & 24) | ((qc ^ xrow) & 7))];
        #pragma unroll
        for (int sub = 0; sub < 4; sub++) {
            int wr = sub * 16 + n;
            bf16x8 a = ((const bf16x8*)Wsh)[wr * 32 + ((qc & 24) | ((qc ^ wr) & 7))];
            acc[sub] = __builtin_amdgcn_mfma_f32_16x16x32_bf16(a, b, acc[sub], 0, 0, 0);
        }
    }

    const int ig = i0 + wave * 16 + n;
    const int bb = ig >> 10, nr = ig & 1023;
    if (ftile < 4) {
        #pragma unroll
        for (int sub = 0; sub < 4; sub++) {
            int dd = sub * 16 + quad * 4;
            ushort4 v = make_ushort4(f2b(acc[sub][0] * 0.125f), f2b(acc[sub][1] * 0.125f),
                                     f2b(acc[sub][2] * 0.125f), f2b(acc[sub][3] * 0.125f));
            *(ushort4*)(Qb + ((size_t)((bb * NH + ftile) * NB + nr)) * 64 + dd) = v;
        }
    } else if (ftile < 8) {
        int h = ftile - 4;
        #pragma unroll
        for (int sub = 0; sub < 4; sub++) {
            int dd = sub * 16 + quad * 4;
            ushort4 v = make_ushort4(f2b(acc[sub][0]), f2b(acc[sub][1]),
                                     f2b(acc[sub][2]), f2b(acc[sub][3]));
            *(ushort4*)(Kb + ((size_t)((bb * NH + h) * NB + nr)) * 64 + dd) = v;
        }
    } else {
        #pragma unroll
        for (int sub = 0; sub < 2; sub++) {
            #pragma unroll
            for (int r = 0; r < 4; r++) {
                int fp = sub * 16 + quad * 4 + r;       // 0..31
                int h2 = fp >> 3, o = fp & 7;
                float bpv = F32 ? ((const float*)bp)[fp]
                                : b2f_u(((const unsigned short*)bp)[fp]);
                float v = acc[sub][r] + bpv;
                int bh = bb * NH + h2;
                PH[(size_t)bh * 8192 + o * 1024 + nr] = v;
                float sv, cv;
                __sincosf(v, &sv, &cv);
                SC[(size_t)(bh * 16 + o) * 1024 + nr]     = f2b(sv);
                SC[(size_t)(bh * 16 + 8 + o) * 1024 + nr] = f2b(cv);
            }
        }
    }
}

__global__ __launch_bounds__(256) void k_projm(
    const unsigned short* x, const void* Wq, const void* Wk, const void* Wp,
    const void* bp, unsigned short* Qb, unsigned short* Kb, float* PH,
    unsigned short* SC)
{
    if (detect_inline(x)) projm_impl<true >(x, Wq, Wk, Wp, bp, Qb, Kb, PH, SC);
    else                  projm_impl<false>(x, Wq, Wk, Wp, bp, Qb, Kb, PH, SC);
}

// ---------------------------------------------------------------------------
// K2: FUSED scores + step1. Grid 512 = 8 bh x 64 chunks of 16 rows; 4 waves.
// Scores phase: wave w computes U rows for j in [w*256,(w+1)*256), writes U
// to global (for steps 2-5) AND into a 32KB xor-swizzled LDS tile. Rowsum ->
// Rsh (+ global R). After one barrier, step-1 MFMA reads A from LDS (no
// global U re-read), B = SC0 direct from global; standard reduce + epilogue.
// Swizzle map: write ushort4 at uint4-col (2*jt+(quad>>1))^(n&7), half quad&1
// <-> read bf16x8 at (it*4+quad)^(n&7). (element-verified)
// ---------------------------------------------------------------------------
__global__ __launch_bounds__(256) void k_scores_step1(
    const unsigned short* __restrict__ xraw,
    const unsigned short* __restrict__ Qb, const unsigned short* __restrict__ Kb,
    unsigned short* __restrict__ U, float* __restrict__ R,
    const float* __restrict__ PHin, float* __restrict__ PHout,
    const unsigned short* __restrict__ SCin, unsigned short* __restrict__ SCout,
    const void* __restrict__ omega, const void* __restrict__ csp)
{
    __shared__ uint4 Ush[16 * 128];   // 32 KB block-private U tile
    __shared__ f32x4 red[4][64];      // 4 KB
    __shared__ float redS[4][16];
    __shared__ float Rsh[16];
    const int tid = threadIdx.x;
    const int bh  = blockIdx.x >> 6;
    const int i0  = (blockIdx.x & 63) * 16;
    const int wave = tid >> 6, lane = tid & 63;
    const int n = lane & 15, quad = lane >> 4;
    const int f32 = detect_inline(xraw);
    const float* phs = PHin + (size_t)bh * 8192;

    // ---- scores phase ----
    const unsigned short* qrow = Qb + ((size_t)(bh * NB) + i0 + n) * 64;
    bf16x8 bq0 = *(const bf16x8*)(qrow + quad * 8);
    bf16x8 bq1 = *(const bf16x8*)(qrow + 32 + quad * 8);
    float s = 0.f;
    unsigned short* urow = U + ((size_t)(bh * NB) + i0 + n) * NB;
    const unsigned short* kbase = Kb + ((size_t)(bh * NB) + n) * 64;
    #pragma unroll
    for (int t = 0; t < 16; t++) {
        int jt = wave * 16 + t;                       // j-tile 0..63
        const unsigned short* arow = kbase + (size_t)jt * 16 * 64;
        bf16x8 a0 = *(const bf16x8*)(arow + quad * 8);
        bf16x8 a1 = *(const bf16x8*)(arow + 32 + quad * 8);
        f32x4 acc = {0.f, 0.f, 0.f, 0.f};
        acc = __builtin_amdgcn_mfma_f32_16x16x32_bf16(a0, bq0, acc, 0, 0, 0);
        acc = __builtin_amdgcn_mfma_f32_16x16x32_bf16(a1, bq1, acc, 0, 0, 0);
        float u0 = __expf(acc[0]);
        float u1 = __expf(acc[1]);
        float u2 = __expf(acc[2]);
        float u3 = __expf(acc[3]);
        s += (u0 + u1) + (u2 + u3);
        ushort4 uv = make_ushort4(f2b(u0), f2b(u1), f2b(u2), f2b(u3));
        *(ushort4*)(urow + jt * 16 + quad * 4) = uv;
        int cw = 2 * jt + (quad >> 1);
        ((ushort4*)Ush)[(n * 128 + (cw ^ (n & 7))) * 2 + (quad & 1)] = uv;
    }
    s += __shfl_xor(s, 16);
    s += __shfl_xor(s, 32);
    if (lane < 16) redS[wave][lane] = s;
    __syncthreads();
    if (tid < 16) {
        float rv = 1.0f / (redS[0][tid] + redS[1][tid] + redS[2][tid] + redS[3][tid]);
        Rsh[tid] = rv;
        R[bh * NB + i0 + tid] = rv;      // for steps 2-5
    }

    // ---- step-1 MFMA phase: A from LDS, B = SC0 from global ----
    const unsigned short* scrow = SCin + (size_t)(bh * 16 + n) * 1024;
    f32x4 acc = {0.f, 0.f, 0.f, 0.f};
    #pragma unroll
    for (int t = 0; t < 8; t++) {
        int it = wave * 8 + t;
        bf16x8 a = ((const bf16x8*)Ush)[n * 128 + ((it * 4 + quad) ^ (n & 7))];
        bf16x8 b = *(const bf16x8*)(scrow + it * 32 + quad * 8);
        acc = __builtin_amdgcn_mfma_f32_16x16x32_bf16(a, b, acc, 0, 0, 0);
    }
    red[wave][lane] = acc;
    __syncthreads();

    if (wave == 0) {
        f32x4 a0 = red[0][lane], a1 = red[1][lane];
        f32x4 a2 = red[2][lane], a3 = red[3][lane];
        #pragma unroll
        for (int v = 0; v < 4; v++) acc[v] = (a0[v] + a1[v]) + (a2[v] + a3[v]);

        float C0 = __shfl_xor(acc[0], 8);
        float C1 = __shfl_xor(acc[1], 8);
        float C2 = __shfl_xor(acc[2], 8);
        float C3 = __shfl_xor(acc[3], 8);

        if (n < 8) {
            const int o = n, h = bh & 3;
            const float cs = f32 ? *(const float*)csp : read_cs_bf16(csp);
            const float om = f32 ? ((const float*)omega)[h * NO + o]
                                 : b2f_u(((const unsigned short*)omega)[h * NO + o]);
            float4 pv = *(const float4*)(phs + o * 1024 + i0 + quad * 4);
            float S[4] = {acc[0], acc[1], acc[2], acc[3]};
            float C[4] = {C0, C1, C2, C3};
            float Rr[4] = {Rsh[quad * 4], Rsh[quad * 4 + 1],
                           Rsh[quad * 4 + 2], Rsh[quad * 4 + 3]};
            float P[4]  = {pv.x, pv.y, pv.z, pv.w};
            float op[4];
            #pragma unroll
            for (int r = 0; r < 4; r++) {
                float si, ci;
                __sincosf(P[r], &si, &ci);
                float coup = (ci * S[r] - si * C[r]) * Rr[r];
                float v = P[r] + 0.1f * (om + cs * coup);
                float t2 = v + PI_F;
                t2 -= floorf(t2 * INV_2PI_F) * TWO_PI_F;   // jnp.remainder
                op[r] = t2 - PI_F;
            }
            *(float4*)(PHout + (size_t)bh * 8192 + o * 1024 + i0 + quad * 4)
                = make_float4(op[0], op[1], op[2], op[3]);
            #pragma unroll
            for (int r = 0; r < 4; r++) {
                float sn, cn;
                __sincosf(op[r], &sn, &cn);
                int i = i0 + quad * 4 + r;
                SCout[(size_t)(bh * 16 + o) * 1024 + i]     = f2b(sn);
                SCout[(size_t)(bh * 16 + 8 + o) * 1024 + i] = f2b(cn);
            }
        }
    }
}

// ---------------------------------------------------------------------------
// K3: Kuramoto step (steps 2-5). Grid 512 = 8 bh x 64 chunks of 16 rows.
// Operands direct from global (U L2/L3-hot, SC L2-hot); 4 KB LDS reduce.
// ---------------------------------------------------------------------------
__global__ __launch_bounds__(256) void k_step(
    const unsigned short* __restrict__ xraw,
    const unsigned short* __restrict__ U, const float* __restrict__ R,
    const float* __restrict__ PHin, float* __restrict__ PHout,
    const unsigned short* __restrict__ SCin, unsigned short* __restrict__ SCout,
    const void* __restrict__ omega, const void* __restrict__ csp)
{
    __shared__ f32x4 red[4][64];      // 4 KB
    const int tid  = threadIdx.x;
    const int bh   = blockIdx.x >> 6;
    const int i0   = (blockIdx.x & 63) * 16;
    const int wave = tid >> 6, lane = tid & 63;
    const int n    = lane & 15, quad = lane >> 4;
    const int f32  = detect_inline(xraw);
    const float* phs = PHin + (size_t)bh * 8192;

    const unsigned short* urow  = U + ((size_t)(bh * NB) + i0 + n) * NB;
    const unsigned short* scrow = SCin + (size_t)(bh * 16 + n) * 1024;
    f32x4 acc = {0.f, 0.f, 0.f, 0.f};
    #pragma unroll
    for (int t = 0; t < 8; t++) {
        int it = wave * 8 + t;
        bf16x8 a = *(const bf16x8*)(urow  + it * 32 + quad * 8);
        bf16x8 b = *(const bf16x8*)(scrow + it * 32 + quad * 8);
        acc = __builtin_amdgcn_mfma_f32_16x16x32_bf16(a, b, acc, 0, 0, 0);
    }
    red[wave][lane] = acc;
    __syncthreads();

    if (wave == 0) {
        f32x4 a0 = red[0][lane], a1 = red[1][lane];
        f32x4 a2 = red[2][lane], a3 = red[3][lane];
        #pragma unroll
        for (int v = 0; v < 4; v++) acc[v] = (a0[v] + a1[v]) + (a2[v] + a3[v]);

        float C0 = __shfl_xor(acc[0], 8);
        float C1 = __shfl_xor(acc[1], 8);
        float C2 = __shfl_xor(acc[2], 8);
        float C3 = __shfl_xor(acc[3], 8);

        if (n < 8) {
            const int o = n, h = bh & 3;
            const float cs = f32 ? *(const float*)csp : read_cs_bf16(csp);
            const float om = f32 ? ((const float*)omega)[h * NO + o]
                                 : b2f_u(((const unsigned short*)omega)[h * NO + o]);
            float4 Rv = *(const float4*)(R + bh * NB + i0 + quad * 4);
            float4 pv = *(const float4*)(phs + o * 1024 + i0 + quad * 4);
            float S[4] = {acc[0], acc[1], acc[2], acc[3]};
            float C[4] = {C0, C1, C2, C3};
            float Rr[4] = {Rv.x, Rv.y, Rv.z, Rv.w};
            float P[4]  = {pv.x, pv.y, pv.z, pv.w};
            float op[4];
            #pragma unroll
            for (int r = 0; r < 4; r++) {
                float si, ci;
                __sincosf(P[r], &si, &ci);
                float coup = (ci * S[r] - si * C[r]) * Rr[r];
                float v = P[r] + 0.1f * (om + cs * coup);
                float t2 = v + PI_F;
                t2 -= floorf(t2 * INV_2PI_F) * TWO_PI_F;   // jnp.remainder
                op[r] = t2 - PI_F;
            }
            *(float4*)(PHout + (size_t)bh * 8192 + o * 1024 + i0 + quad * 4)
                = make_float4(op[0], op[1], op[2], op[3]);
            #pragma unroll
            for (int r = 0; r < 4; r++) {
                float sn, cn;
                __sincosf(op[r], &sn, &cn);
                int i = i0 + quad * 4 + r;
                SCout[(size_t)(bh * 16 + o) * 1024 + i]     = f2b(sn);
                SCout[(size_t)(bh * 16 + 8 + o) * 1024 + i] = f2b(cn);
            }
        }
    }
}

// ---------------------------------------------------------------------------
// K4: out = SC_cos @ Wo.T + bo. Grid 256 = 2 b x 128 chunks of 8 n.
// Wo row (32 f32) cached in VGPRs, reused across 8 rows.
// ---------------------------------------------------------------------------
__global__ __launch_bounds__(256) void k_out(
    const unsigned short* __restrict__ xraw,
    const unsigned short* __restrict__ SC,
    const void* __restrict__ Wo, const void* __restrict__ bo,
    void* __restrict__ out)
{
    __shared__ float sig[8 * 32];
    const int tid = threadIdx.x;
    const int b  = blockIdx.x >> 7;
    const int n0 = (blockIdx.x & 127) * 8;
    const int f32 = detect_inline(xraw);

    {   // stage cos for 8 rows x 32 features
        int r = tid >> 5, f = tid & 31;
        int h = f >> 3, o = f & 7;
        sig[r * 32 + f] = b2f_u(SC[(size_t)((b * NH + h) * 16 + 8 + o) * 1024 + n0 + r]);
    }
    __syncthreads();

    float wv[32];
    #pragma unroll
    for (int d0 = 0; d0 < 32; d0 += 8) load8_rt(f32, Wo, tid * 32 + d0, wv + d0);
    const float bov = f32 ? ((const float*)bo)[tid] : b2f_u(((const unsigned short*)bo)[tid]);

    #pragma unroll
    for (int r = 0; r < 8; r++) {
        float acc = bov;
        #pragma unroll
        for (int t = 0; t < 32; t++) acc += sig[r * 32 + t] * wv[t];
        size_t oi = ((size_t)b * 1024 + n0 + r) * DD + tid;
        if (f32) ((float*)out)[oi] = acc;
        else     ((unsigned short*)out)[oi] = f2b(acc);
    }
}

// ---------------------------------------------------------------------------
extern "C" void kernel_launch(void* const* d_in, const int* in_sizes, int n_in,
                              void* d_out, int out_size, void* d_ws, size_t ws_size,
                              hipStream_t stream)
{
    const unsigned short* x = (const unsigned short*)d_in[0];
    const void* Wq  = d_in[1];
    const void* Wk  = d_in[2];
    const void* Wp  = d_in[3];
    const void* bp  = d_in[4];
    const void* Wo  = d_in[5];
    const void* bo  = d_in[6];
    const void* om  = d_in[7];
    const void* cs  = d_in[8];

    char* w = (char*)d_ws;
    unsigned short* Qb  = (unsigned short*)w;
    unsigned short* Kb  = (unsigned short*)(w + (1u << 20));
    float*          R   = (float*)(w + (2u << 20));
    float*          PH0 = (float*)(w + (2u << 20) + (64u << 10));
    float*          PH1 = (float*)(w + (2u << 20) + (320u << 10));
    unsigned short* SC0 = (unsigned short*)(w + (2u << 20) + (576u << 10));
    unsigned short* SC1 = (unsigned short*)(w + (2u << 20) + (832u << 10));
    unsigned short* U   = (unsigned short*)(w + (2u << 20) + (1088u << 10));

    k_projm<<<288, 256, 0, stream>>>(x, Wq, Wk, Wp, bp, Qb, Kb, PH0, SC0);
    // fused scores + step 1: PH0/SC0 -> PH1/SC1
    k_scores_step1<<<512, 256, 0, stream>>>(x, Qb, Kb, U, R, PH0, PH1, SC0, SC1, om, cs);
    // steps 2-5
    k_step<<<512, 256, 0, stream>>>(x, U, R, PH1, PH0, SC1, SC0, om, cs);
    k_step<<<512, 256, 0, stream>>>(x, U, R, PH0, PH1, SC0, SC1, om, cs);
    k_step<<<512, 256, 0, stream>>>(x, U, R, PH1, PH0, SC1, SC0, om, cs);
    k_step<<<512, 256, 0, stream>>>(x, U, R, PH0, PH1, SC0, SC1, om, cs);
    k_out<<<256, 256, 0, stream>>>(x, SC1, Wo, bo, d_out);
}